// Round 1
// baseline (231.316 us; speedup 1.0000x reference)
//
#include <hip/hip_runtime.h>
#include <stdint.h>

// DCN v1 forward: B=8, C=256, H=W=64, K=3, pad=1, stride=1, O=256.
// Strategy: fused im2col+GEMM with bf16 MFMA (harness threshold is bf16-scale).
//   kernel 1: weight -> bf16, reordered kk = k2*256+c, pre-tiled per K-step
//   kernel 2: x -> channels-last bf16 xT[b][p][c] (coalesced c-contiguous gathers)
//   kernel 3: fused bilinear-sample + 128x128 MFMA tile GEMM
// ws layout: [0, 1179648) = wt tiles; [1179648, +16777216) = xT.

#define Bb 8
#define Cc 256
#define Hh 64
#define Ww 64
#define Pp 4096      // H*W
#define Oo 256
#define NK2 9
#define BM 128
#define BN 128
#define BK 32
#define CCH 8        // C / BK
#define KSTEPS 72    // NK2 * CCH
#define WT_BYTES (2u * KSTEPS * BM * BK * 2u)  // 1,179,648

typedef __attribute__((ext_vector_type(4))) float f32x4;
typedef __attribute__((ext_vector_type(8))) short s16x8;
typedef __attribute__((ext_vector_type(4))) int   i32x4;

static __device__ __forceinline__ unsigned short f2bf(float f) {
    union { float f; uint32_t u; } v; v.f = f;
    return (unsigned short)((v.u + 0x7fffu + ((v.u >> 16) & 1u)) >> 16);  // RNE
}
static __device__ __forceinline__ float bf2f(unsigned short h) {
    union { uint32_t u; float f; } v; v.u = ((uint32_t)h) << 16; return v.f;
}
static __device__ __forceinline__ int imin(int a, int b) { return a < b ? a : b; }
static __device__ __forceinline__ int imax(int a, int b) { return a > b ? a : b; }

// weight[o][ch][ky][kx] fp32 -> wt tiled bf16: [octile(2)][kstep(72)][row=oc(128)][col=c32(32)]
// kstep = k2*8 + cch ; channel = cch*32 + c32 ; kk order = k2-major, c-minor.
__global__ void prep_weight(const float* __restrict__ w, unsigned short* __restrict__ wt) {
    int tid = blockIdx.x * 256 + threadIdx.x;          // 0 .. 589823, == output linear idx
    int c32 = tid & 31;
    int r = (tid >> 5) & 127;
    int t12 = tid >> 12;
    int kstep = t12 % KSTEPS;
    int octile = t12 / KSTEPS;
    int k2 = kstep >> 3, cch = kstep & 7;
    int o = octile * 128 + r;
    int ch = cch * 32 + c32;
    wt[tid] = f2bf(w[(o * Cc + ch) * NK2 + k2]);
}

// x[b][c][p] fp32 -> xT[b][p][c] bf16, 64x64 LDS tile transpose
__global__ void prep_x(const float* __restrict__ x, unsigned short* __restrict__ xt) {
    __shared__ unsigned short t[64][65];               // +1 pad breaks bank conflicts
    int b = blockIdx.z, c0 = blockIdx.y * 64, p0 = blockIdx.x * 64;
    int tl = threadIdx.x & 63, tg = threadIdx.x >> 6;  // 4 row-groups
    #pragma unroll
    for (int r = 0; r < 16; r++) {
        int cr = r * 4 + tg;
        t[cr][tl] = f2bf(x[((size_t)(b * Cc + c0 + cr) * Pp) + p0 + tl]);
    }
    __syncthreads();
    #pragma unroll
    for (int r = 0; r < 16; r++) {
        int pr = r * 4 + tg;
        xt[((size_t)(b * Pp + p0 + pr) * Cc) + c0 + tl] = t[tl][pr];
    }
}

// Fused sampler + GEMM. Block: 256 thr = 4 waves (2x2 of 64x64). Grid: (32 ptiles, 2 octiles, 8 b).
__global__ __launch_bounds__(256, 2)
void dcn_main(const float* __restrict__ off, const unsigned short* __restrict__ wt,
              const unsigned short* __restrict__ xt, float* __restrict__ out) {
    __shared__ unsigned short Alds[BM * BK];   // [oc 128][kk 32] row-major, 8 KB
    __shared__ unsigned short Slds[BN * BK];   // [px 128][c 32]  row-major, 8 KB
    __shared__ int   tidx[128][4];             // 4 bilinear tap indices per pixel
    __shared__ float twgt[128][4];             // 4 tap weights (0 if OOB)

    const int b = blockIdx.z;
    const int octile = blockIdx.y;
    const int p0 = blockIdx.x * BN;

    const int tid  = threadIdx.x;
    const int lane = tid & 63;
    const int wave = tid >> 6;
    const int quad = lane >> 4;
    const int l16  = lane & 15;
    const int moff = (wave & 1) * 64;
    const int noff = (wave >> 1) * 64;

    // sampling mapping: 4 lanes/pixel cover 32 channels (8 each); 64 groups x 2 pixels
    const int cquad = tid & 3;
    const int sg    = tid >> 2;

    const unsigned short* xtb = xt + (size_t)b * Pp * Cc;

    f32x4 acc[4][4];
    #pragma unroll
    for (int i = 0; i < 4; i++)
        #pragma unroll
        for (int j = 0; j < 4; j++) acc[i][j] = (f32x4){0.f, 0.f, 0.f, 0.f};

    for (int k2 = 0; k2 < NK2; k2++) {
        // ---- taps for this kernel point (once per k2, shared by 8 c-chunks) ----
        if (tid < 128) {
            int pl = p0 + tid;
            int hh = pl >> 6, ww = pl & 63;
            int ky = k2 / 3, kx = k2 - ky * 3;
            float dy = off[((size_t)(b * 18 + 2 * k2    ) * Pp) + pl];
            float dx = off[((size_t)(b * 18 + 2 * k2 + 1) * Pp) + pl];
            float py  = (float)(hh - 1 + ky) + dy;
            float pxf = (float)(ww - 1 + kx) + dx;
            float y0f = floorf(py), x0f = floorf(pxf);
            int   y0 = (int)y0f,  x0 = (int)x0f;
            int   y1 = y0 + 1,    x1 = x0 + 1;
            float ly = py - y0f,  lx = pxf - x0f;
            float oy = 1.f - ly,  ox = 1.f - lx;
            bool vy0 = (y0 >= 0) && (y0 < Hh);
            bool vy1 = (y1 >= 0) && (y1 < Hh);
            bool vx0 = (x0 >= 0) && (x0 < Ww);
            bool vx1 = (x1 >= 0) && (x1 < Ww);
            int cy0 = imin(imax(y0, 0), Hh - 1), cy1 = imin(imax(y1, 0), Hh - 1);
            int cx0 = imin(imax(x0, 0), Ww - 1), cx1 = imin(imax(x1, 0), Ww - 1);
            tidx[tid][0] = cy0 * Ww + cx0;  twgt[tid][0] = (vy0 && vx0) ? oy * ox : 0.f;
            tidx[tid][1] = cy0 * Ww + cx1;  twgt[tid][1] = (vy0 && vx1) ? oy * lx : 0.f;
            tidx[tid][2] = cy1 * Ww + cx0;  twgt[tid][2] = (vy1 && vx0) ? ly * ox : 0.f;
            tidx[tid][3] = cy1 * Ww + cx1;  twgt[tid][3] = (vy1 && vx1) ? ly * lx : 0.f;
        }
        __syncthreads();

        // register-cache taps for this thread's two pixels (reused across 8 c-chunks)
        i32x4 ti0 = *(const i32x4*)&tidx[sg][0];
        f32x4 tw0 = *(const f32x4*)&twgt[sg][0];
        i32x4 ti1 = *(const i32x4*)&tidx[64 + sg][0];
        f32x4 tw1 = *(const f32x4*)&twgt[64 + sg][0];

        for (int cch = 0; cch < CCH; cch++) {
            // ---- stage A-tile (contiguous 8 KB, coalesced b128) ----
            const unsigned short* wsrc =
                wt + ((size_t)(octile * KSTEPS + (k2 * 8 + cch)) << 12);
            s16x8 a0 = *(const s16x8*)(wsrc + tid * 8);
            s16x8 a1 = *(const s16x8*)(wsrc + 2048 + tid * 8);
            *(s16x8*)&Alds[tid * 8] = a0;
            *(s16x8*)&Alds[2048 + tid * 8] = a1;

            // ---- bilinear sample 32 channels x 128 px into Slds[px][c] ----
            const unsigned short* cbase = xtb + cch * 32 + cquad * 8;
            #pragma unroll
            for (int i = 0; i < 2; i++) {
                i32x4 ti = i ? ti1 : ti0;
                f32x4 tw = i ? tw1 : tw0;
                float s[8];
                #pragma unroll
                for (int j = 0; j < 8; j++) s[j] = 0.f;
                #pragma unroll
                for (int t = 0; t < 4; t++) {
                    s16x8 v = *(const s16x8*)(cbase + (size_t)ti[t] * Cc);  // 16B gather
                    float wg = tw[t];
                    #pragma unroll
                    for (int j = 0; j < 8; j++) s[j] += wg * bf2f((unsigned short)v[j]);
                }
                s16x8 pk;
                #pragma unroll
                for (int j = 0; j < 8; j++) pk[j] = (short)f2bf(s[j]);
                int pxl = i * 64 + sg;
                *(s16x8*)&Slds[pxl * 32 + cquad * 8] = pk;
            }
            __syncthreads();

            // ---- MFMA 64x64 per wave: 4x4 tiles of 16x16x32 ----
            s16x8 af[4], bfr[4];
            #pragma unroll
            for (int mt = 0; mt < 4; mt++)
                af[mt] = *(const s16x8*)&Alds[(moff + mt * 16 + l16) * 32 + quad * 8];
            #pragma unroll
            for (int nt = 0; nt < 4; nt++)
                bfr[nt] = *(const s16x8*)&Slds[(noff + nt * 16 + l16) * 32 + quad * 8];
            #pragma unroll
            for (int mt = 0; mt < 4; mt++)
                #pragma unroll
                for (int nt = 0; nt < 4; nt++)
                    acc[mt][nt] = __builtin_amdgcn_mfma_f32_16x16x32_bf16(
                        af[mt], bfr[nt], acc[mt][nt], 0, 0, 0);
            __syncthreads();
        }
    }

    // ---- epilogue: C/D layout row(m)=quad*4+r, col(n)=l16 ----
    float* op = out + ((size_t)(b * Oo + octile * 128) * Pp) + p0;
    #pragma unroll
    for (int mt = 0; mt < 4; mt++)
        #pragma unroll
        for (int nt = 0; nt < 4; nt++)
            #pragma unroll
            for (int r = 0; r < 4; r++) {
                int o_ = moff + mt * 16 + quad * 4 + r;
                int p_ = noff + nt * 16 + l16;
                op[(size_t)o_ * Pp + p_] = acc[mt][nt][r];
            }
}

extern "C" void kernel_launch(void* const* d_in, const int* in_sizes, int n_in,
                              void* d_out, int out_size, void* d_ws, size_t ws_size,
                              hipStream_t stream) {
    (void)in_sizes; (void)n_in; (void)out_size; (void)ws_size;
    const float* x   = (const float*)d_in[0];
    const float* off = (const float*)d_in[1];
    const float* w   = (const float*)d_in[2];
    float* out = (float*)d_out;

    unsigned short* wt = (unsigned short*)d_ws;
    unsigned short* xt = (unsigned short*)((char*)d_ws + WT_BYTES);

    hipLaunchKernelGGL(prep_weight, dim3(2304), dim3(256), 0, stream, w, wt);
    hipLaunchKernelGGL(prep_x, dim3(64, 4, 8), dim3(256), 0, stream, x, xt);
    hipLaunchKernelGGL(dcn_main, dim3(32, 2, 8), dim3(256), 0, stream, off, wt, xt, out);
}

// Round 2
// 199.773 us; speedup vs baseline: 1.1579x; 1.1579x over previous
//
#include <hip/hip_runtime.h>
#include <stdint.h>

// DCN v1 forward: B=8, C=256, H=W=64, K=3, pad=1, stride=1, O=256.
// Round 2: BM=256 x BN=64 fused tile (sampling done ONCE per pixel),
// 512-thr blocks (8 waves -> 16 waves/CU), single-sync pipelined K-loop with
// double-buffered S, A-frags direct from L2-resident pre-tiled weights,
// padded S stride (80 B) for ~conflict-free b128, v_perm truncation pack.

#define Bb 8
#define Cc 256
#define Hh 64
#define Ww 64
#define Pp 4096
#define Oo 256
#define NK2 9
#define KSTEPS 72            // 9 k2 * 8 c-chunks of 32
#define BN 64
#define SROW 40              // padded row stride (elems) for S tiles
#define WT_BYTES (2u * KSTEPS * 256u * 32u)  // 1,179,648

typedef __attribute__((ext_vector_type(4))) float f32x4;
typedef __attribute__((ext_vector_type(8))) short s16x8;
typedef __attribute__((ext_vector_type(4))) int   i32x4;

static __device__ __forceinline__ unsigned short f2bf(float f) {
    union { float f; uint32_t u; } v; v.f = f;
    return (unsigned short)((v.u + 0x7fffu + ((v.u >> 16) & 1u)) >> 16);  // RNE
}
static __device__ __forceinline__ int imin(int a, int b) { return a < b ? a : b; }
static __device__ __forceinline__ int imax(int a, int b) { return a > b ? a : b; }

// weight[o][ch][ky][kx] fp32 -> wt bf16 [kstep(72)][row=oc(256)][col=c32(32)]
__global__ void prep_weight(const float* __restrict__ w, unsigned short* __restrict__ wt) {
    int tid = blockIdx.x * 256 + threadIdx.x;      // 0..589823 linear out idx
    int c32 = tid & 31;
    int row = (tid >> 5) & 255;
    int ks  = tid >> 13;                            // 0..71
    int k2 = ks >> 3, cch = ks & 7;
    wt[tid] = f2bf(w[(row * Cc + cch * 32 + c32) * NK2 + k2]);
}

// x[b][c][p] fp32 -> xT[b][p][c] bf16 (channels-last), 64x64 LDS transpose
__global__ void prep_x(const float* __restrict__ x, unsigned short* __restrict__ xt) {
    __shared__ unsigned short t[64][65];
    int b = blockIdx.z, c0 = blockIdx.y * 64, p0 = blockIdx.x * 64;
    int tl = threadIdx.x & 63, tg = threadIdx.x >> 6;
    #pragma unroll
    for (int r = 0; r < 16; r++) {
        int cr = r * 4 + tg;
        t[cr][tl] = f2bf(x[((size_t)(b * Cc + c0 + cr) * Pp) + p0 + tl]);
    }
    __syncthreads();
    #pragma unroll
    for (int r = 0; r < 16; r++) {
        int pr = r * 4 + tg;
        xt[((size_t)(b * Pp + p0 + pr) * Cc) + c0 + tl] = t[tl][pr];
    }
}

// Fused sampler + GEMM. Block: 512 thr = 8 waves, M=256 (4 mwaves) x N=64 (2 nwaves).
// Grid: (64 ptiles, 1, 8 batches) = 512 blocks -> 2 blocks/CU, 16 waves/CU.
__global__ __launch_bounds__(512, 4)
void dcn_main(const float* __restrict__ off, const unsigned short* __restrict__ wt,
              const unsigned short* __restrict__ xt, float* __restrict__ out) {
    __shared__ __align__(16) unsigned short Sl[2][BN * SROW];  // 2 x 5120 B
    __shared__ __align__(16) int   tidx[NK2][BN][4];           // 9216 B, byte offsets (idx*512)
    __shared__ __align__(16) float twgt[NK2][BN][4];           // 9216 B

    const int b   = blockIdx.z;
    const int p0  = blockIdx.x * BN;
    const int tid = threadIdx.x;
    const int lane = tid & 63;
    const int wv   = tid >> 6;
    const int quad = lane >> 4;
    const int l16  = lane & 15;
    const int moff = (wv & 3) * 64;
    const int noff = (wv >> 2) * 32;

    // sampler mapping: 8 threads per pixel, 4 channels each
    const int px  = tid >> 3;    // 0..63
    const int sub = tid & 7;     // 0..7

    const char* xtb = (const char*)xt + (size_t)b * Pp * Cc * 2;

    // ---- taps for all 9 kernel points (once per block) ----
    for (int t = tid; t < NK2 * BN; t += 512) {
        int k2 = t >> 6, pxl = t & 63;
        int pl = p0 + pxl;
        int hh = pl >> 6, ww = pl & 63;
        int ky = k2 / 3, kx = k2 - ky * 3;
        float dy = off[((size_t)(b * 18 + 2 * k2    ) * Pp) + pl];
        float dx = off[((size_t)(b * 18 + 2 * k2 + 1) * Pp) + pl];
        float py  = (float)(hh - 1 + ky) + dy;
        float pxf = (float)(ww - 1 + kx) + dx;
        float y0f = floorf(py), x0f = floorf(pxf);
        int   y0 = (int)y0f,  x0 = (int)x0f;
        int   y1 = y0 + 1,    x1 = x0 + 1;
        float ly = py - y0f,  lx = pxf - x0f;
        float oy = 1.f - ly,  ox = 1.f - lx;
        bool vy0 = (y0 >= 0) && (y0 < Hh);
        bool vy1 = (y1 >= 0) && (y1 < Hh);
        bool vx0 = (x0 >= 0) && (x0 < Ww);
        bool vx1 = (x1 >= 0) && (x1 < Ww);
        int cy0 = imin(imax(y0, 0), Hh - 1), cy1 = imin(imax(y1, 0), Hh - 1);
        int cx0 = imin(imax(x0, 0), Ww - 1), cx1 = imin(imax(x1, 0), Ww - 1);
        tidx[k2][pxl][0] = (cy0 * Ww + cx0) * 512;  twgt[k2][pxl][0] = (vy0 && vx0) ? oy * ox : 0.f;
        tidx[k2][pxl][1] = (cy0 * Ww + cx1) * 512;  twgt[k2][pxl][1] = (vy0 && vx1) ? oy * lx : 0.f;
        tidx[k2][pxl][2] = (cy1 * Ww + cx0) * 512;  twgt[k2][pxl][2] = (vy1 && vx0) ? ly * ox : 0.f;
        tidx[k2][pxl][3] = (cy1 * Ww + cx1) * 512;  twgt[k2][pxl][3] = (vy1 && vx1) ? ly * lx : 0.f;
    }
    __syncthreads();

    int   tio[4];
    float twv[4];
    {
        i32x4 ti = *(const i32x4*)&tidx[0][px][0];
        f32x4 tw = *(const f32x4*)&twgt[0][px][0];
        #pragma unroll
        for (int t = 0; t < 4; t++) { tio[t] = ti[t]; twv[t] = tw[t]; }
    }

    // sample 4 channels x 4 taps for K-step ksn into Sl[ksn&1]
    auto sample_into = [&](int ksn) {
        int coff = (ksn & 7) * 64 + sub * 8;       // byte offset within a pixel row
        float s0 = 0.f, s1 = 0.f, s2 = 0.f, s3 = 0.f;
        #pragma unroll
        for (int t = 0; t < 4; t++) {
            uint2 v = *(const uint2*)(xtb + tio[t] + coff);
            float wg = twv[t];
            s0 += wg * __uint_as_float(v.x << 16);
            s1 += wg * __uint_as_float(v.x & 0xffff0000u);
            s2 += wg * __uint_as_float(v.y << 16);
            s3 += wg * __uint_as_float(v.y & 0xffff0000u);
        }
        // truncation-pack 4 f32 -> 4 bf16 (2 perms)
        uint32_t d0 = __builtin_amdgcn_perm(__float_as_uint(s1), __float_as_uint(s0), 0x07060302u);
        uint32_t d1 = __builtin_amdgcn_perm(__float_as_uint(s3), __float_as_uint(s2), 0x07060302u);
        uint2 dd; dd.x = d0; dd.y = d1;
        *(uint2*)((char*)&Sl[ksn & 1][0] + px * (SROW * 2) + sub * 8) = dd;
    };

    f32x4 acc[4][2];
    #pragma unroll
    for (int mt = 0; mt < 4; mt++)
        #pragma unroll
        for (int nt = 0; nt < 2; nt++) acc[mt][nt] = (f32x4){0.f, 0.f, 0.f, 0.f};

    sample_into(0);

    for (int ks = 0; ks < KSTEPS; ks++) {
        __syncthreads();   // Sl[ks&1] writes (prev iter) now visible

        // A fragments straight from global (L2-resident, coalesced 1KB/instr)
        const char* wb = (const char*)wt + ((size_t)ks << 14);
        s16x8 af[4];
        #pragma unroll
        for (int mt = 0; mt < 4; mt++)
            af[mt] = *(const s16x8*)(wb + (moff + mt * 16 + l16) * 64 + quad * 16);

        // pipeline: sample next K-step into the other buffer
        int ksn = ks + 1;
        if (ksn < KSTEPS) {
            if ((ksn & 7) == 0) {            // new kernel point: reload taps (broadcast reads)
                int k2 = ksn >> 3;
                i32x4 ti = *(const i32x4*)&tidx[k2][px][0];
                f32x4 tw = *(const f32x4*)&twgt[k2][px][0];
                #pragma unroll
                for (int t = 0; t < 4; t++) { tio[t] = ti[t]; twv[t] = tw[t]; }
            }
            sample_into(ksn);
        }

        // B fragments + MFMA on current buffer
        const char* sb = (const char*)&Sl[ks & 1][0];
        s16x8 bfr[2];
        #pragma unroll
        for (int nt = 0; nt < 2; nt++)
            bfr[nt] = *(const s16x8*)(sb + (noff + nt * 16 + l16) * (SROW * 2) + quad * 16);
        #pragma unroll
        for (int mt = 0; mt < 4; mt++)
            #pragma unroll
            for (int nt = 0; nt < 2; nt++)
                acc[mt][nt] = __builtin_amdgcn_mfma_f32_16x16x32_bf16(
                    af[mt], bfr[nt], acc[mt][nt], 0, 0, 0);
    }

    // epilogue: C/D layout row(m)=quad*4+r, col(n)=l16
    float* op = out + ((size_t)b * Oo) * Pp + p0;
    #pragma unroll
    for (int mt = 0; mt < 4; mt++)
        #pragma unroll
        for (int nt = 0; nt < 2; nt++)
            #pragma unroll
            for (int r = 0; r < 4; r++) {
                int o_ = moff + mt * 16 + quad * 4 + r;
                int p_ = noff + nt * 16 + l16;
                op[(size_t)o_ * Pp + p_] = acc[mt][nt][r];
            }
}

extern "C" void kernel_launch(void* const* d_in, const int* in_sizes, int n_in,
                              void* d_out, int out_size, void* d_ws, size_t ws_size,
                              hipStream_t stream) {
    (void)in_sizes; (void)n_in; (void)out_size; (void)ws_size;
    const float* x   = (const float*)d_in[0];
    const float* off = (const float*)d_in[1];
    const float* w   = (const float*)d_in[2];
    float* out = (float*)d_out;

    unsigned short* wt = (unsigned short*)d_ws;
    unsigned short* xt = (unsigned short*)((char*)d_ws + WT_BYTES);

    hipLaunchKernelGGL(prep_weight, dim3(2304), dim3(256), 0, stream, w, wt);
    hipLaunchKernelGGL(prep_x, dim3(64, 4, 8), dim3(256), 0, stream, x, xt);
    hipLaunchKernelGGL(dcn_main, dim3(64, 1, 8), dim3(512), 0, stream, off, wt, xt, out);
}

// Round 3
// 165.692 us; speedup vs baseline: 1.3961x; 1.2057x over previous
//
#include <hip/hip_runtime.h>
#include <stdint.h>

// DCN v1 forward: B=8, C=256, H=W=64, K=3, pad=1, stride=1, O=256.
// Round 3: XCD batch-affinity swizzle (b = blockIdx.x & 7 -> per-XCD L2-resident
// xT slice), pair-K-step loop (BK=64, 36 barriers, 16-B gathers), 32x64 wave
// tiling (8 m-groups -> zero A-fragment duplication), SROW=40 uniform banking.

#define Bb 8
#define Cc 256
#define Hh 64
#define Ww 64
#define Pp 4096
#define Oo 256
#define NK2 9
#define NPAIR 36             // 36 pairs of K-steps (BK=64 each), 72 ks total
#define BN 64
#define SROW 40              // padded row stride (elems); 80 B -> uniform 8/bank
#define WT_BYTES (2u * 72u * 256u * 32u)  // 1,179,648

typedef __attribute__((ext_vector_type(4))) float f32x4;
typedef __attribute__((ext_vector_type(8))) short s16x8;
typedef __attribute__((ext_vector_type(4))) int   i32x4;

static __device__ __forceinline__ unsigned short f2bf(float f) {
    union { float f; uint32_t u; } v; v.f = f;
    return (unsigned short)((v.u + 0x7fffu + ((v.u >> 16) & 1u)) >> 16);  // RNE
}
static __device__ __forceinline__ int imin(int a, int b) { return a < b ? a : b; }
static __device__ __forceinline__ int imax(int a, int b) { return a > b ? a : b; }

// weight[o][c][ky][kx] fp32 -> wt bf16 [ks(72)][row=oc(256)][c32(32)]
// ks = k2*8+cch, channel = cch*32+c32. Coalesced read, LDS, coalesced write.
__global__ void prep_weight(const float* __restrict__ w, unsigned short* __restrict__ wt) {
    __shared__ unsigned short Lw[8][2304];
    int o0 = blockIdx.x * 8, tid = threadIdx.x;
    for (int r = 0; r < 8; r++)
        for (int i = tid; i < 2304; i += 256)
            Lw[r][i] = f2bf(w[(o0 + r) * 2304 + i]);
    __syncthreads();
    int r = tid >> 5, c32 = tid & 31;
    for (int ks = 0; ks < 72; ks++) {
        int c = (ks & 7) * 32 + c32, k2 = ks >> 3;
        wt[ks * 8192 + (o0 + r) * 32 + c32] = Lw[r][c * 9 + k2];
    }
}

// x[b][c][p] fp32 -> xT[b][p][c] bf16 (channels-last), 64x64 LDS transpose
__global__ void prep_x(const float* __restrict__ x, unsigned short* __restrict__ xt) {
    __shared__ unsigned short t[64][65];
    int b = blockIdx.z, c0 = blockIdx.y * 64, p0 = blockIdx.x * 64;
    int tl = threadIdx.x & 63, tg = threadIdx.x >> 6;
    #pragma unroll
    for (int r = 0; r < 16; r++) {
        int cr = r * 4 + tg;
        t[cr][tl] = f2bf(x[((size_t)(b * Cc + c0 + cr) * Pp) + p0 + tl]);
    }
    __syncthreads();
    #pragma unroll
    for (int r = 0; r < 16; r++) {
        int pr = r * 4 + tg;
        xt[((size_t)(b * Pp + p0 + pr) * Cc) + c0 + tl] = t[tl][pr];
    }
}

// Fused sampler + GEMM. Block: 512 thr = 8 waves, each wave 32(M) x 64(N).
// Grid: 512 blocks flat; b = bx & 7 (XCD affinity), ptile = bx >> 3.
__global__ __launch_bounds__(512, 4)
void dcn_main(const float* __restrict__ off, const unsigned short* __restrict__ wt,
              const unsigned short* __restrict__ xt, float* __restrict__ out) {
    __shared__ __align__(16) unsigned short Sl[2][2][BN][SROW];  // 20480 B
    __shared__ __align__(16) int   tidx[NK2][BN][4];             // 9216 B (byte offs, idx*512)
    __shared__ __align__(16) float twgt[NK2][BN][4];             // 9216 B

    const int b   = blockIdx.x & 7;
    const int p0  = (blockIdx.x >> 3) * BN;
    const int tid = threadIdx.x;
    const int lane = tid & 63;
    const int wv   = tid >> 6;
    const int quad = lane >> 4;
    const int l16  = lane & 15;
    const int moff = wv * 32;

    // sampler mapping: 8 threads/pixel; sub -> 8 channels = (sub>>2 cch-half)*32 + (sub&3)*8
    const int px  = tid >> 3;
    const int sub = tid & 7;
    const int hh_ = sub >> 2;          // which 32-ch half of the pair
    const int cc_ = (sub & 3) * 8;     // channel offset within the half

    const char* xtb = (const char*)xt + (size_t)b * Pp * Cc * 2;

    // ---- taps for all 9 kernel points (once per block) ----
    for (int t = tid; t < NK2 * BN; t += 512) {
        int k2 = t >> 6, pxl = t & 63;
        int pl = p0 + pxl;
        int hh = pl >> 6, ww = pl & 63;
        int ky = k2 / 3, kx = k2 - ky * 3;
        float dy = off[((size_t)(b * 18 + 2 * k2    ) * Pp) + pl];
        float dx = off[((size_t)(b * 18 + 2 * k2 + 1) * Pp) + pl];
        float py  = (float)(hh - 1 + ky) + dy;
        float pxf = (float)(ww - 1 + kx) + dx;
        float y0f = floorf(py), x0f = floorf(pxf);
        int   y0 = (int)y0f,  x0 = (int)x0f;
        int   y1 = y0 + 1,    x1 = x0 + 1;
        float ly = py - y0f,  lx = pxf - x0f;
        float oy = 1.f - ly,  ox = 1.f - lx;
        bool vy0 = (y0 >= 0) && (y0 < Hh);
        bool vy1 = (y1 >= 0) && (y1 < Hh);
        bool vx0 = (x0 >= 0) && (x0 < Ww);
        bool vx1 = (x1 >= 0) && (x1 < Ww);
        int cy0 = imin(imax(y0, 0), Hh - 1), cy1 = imin(imax(y1, 0), Hh - 1);
        int cx0 = imin(imax(x0, 0), Ww - 1), cx1 = imin(imax(x1, 0), Ww - 1);
        tidx[k2][pxl][0] = (cy0 * Ww + cx0) * 512;  twgt[k2][pxl][0] = (vy0 && vx0) ? oy * ox : 0.f;
        tidx[k2][pxl][1] = (cy0 * Ww + cx1) * 512;  twgt[k2][pxl][1] = (vy0 && vx1) ? oy * lx : 0.f;
        tidx[k2][pxl][2] = (cy1 * Ww + cx0) * 512;  twgt[k2][pxl][2] = (vy1 && vx0) ? ly * ox : 0.f;
        tidx[k2][pxl][3] = (cy1 * Ww + cx1) * 512;  twgt[k2][pxl][3] = (vy1 && vx1) ? ly * lx : 0.f;
    }
    __syncthreads();

    int   tio[4];
    float twv[4];
    {
        i32x4 ti = *(const i32x4*)&tidx[0][px][0];
        f32x4 tw = *(const f32x4*)&twgt[0][px][0];
        #pragma unroll
        for (int t = 0; t < 4; t++) { tio[t] = ti[t]; twv[t] = tw[t]; }
    }

    // sample pair pr: 8 channels x 4 taps, one 16-B gather per tap
    auto sample_into = [&](int pr) {
        int coff = (pr & 3) * 128 + sub * 16;     // byte offset within 512-B pixel row
        float s[8];
        #pragma unroll
        for (int j = 0; j < 8; j++) s[j] = 0.f;
        #pragma unroll
        for (int t = 0; t < 4; t++) {
            uint4 v = *(const uint4*)(xtb + tio[t] + coff);
            float wg = twv[t];
            s[0] += wg * __uint_as_float(v.x << 16);
            s[1] += wg * __uint_as_float(v.x & 0xffff0000u);
            s[2] += wg * __uint_as_float(v.y << 16);
            s[3] += wg * __uint_as_float(v.y & 0xffff0000u);
            s[4] += wg * __uint_as_float(v.z << 16);
            s[5] += wg * __uint_as_float(v.z & 0xffff0000u);
            s[6] += wg * __uint_as_float(v.w << 16);
            s[7] += wg * __uint_as_float(v.w & 0xffff0000u);
        }
        uint4 d;
        d.x = __builtin_amdgcn_perm(__float_as_uint(s[1]), __float_as_uint(s[0]), 0x07060302u);
        d.y = __builtin_amdgcn_perm(__float_as_uint(s[3]), __float_as_uint(s[2]), 0x07060302u);
        d.z = __builtin_amdgcn_perm(__float_as_uint(s[5]), __float_as_uint(s[4]), 0x07060302u);
        d.w = __builtin_amdgcn_perm(__float_as_uint(s[7]), __float_as_uint(s[6]), 0x07060302u);
        *(uint4*)&Sl[pr & 1][hh_][px][cc_] = d;
    };

    f32x4 acc[2][4];
    #pragma unroll
    for (int mt = 0; mt < 2; mt++)
        #pragma unroll
        for (int nt = 0; nt < 4; nt++) acc[mt][nt] = (f32x4){0.f, 0.f, 0.f, 0.f};

    sample_into(0);

    for (int pr = 0; pr < NPAIR; pr++) {
        __syncthreads();   // Sl[pr&1] writes (prev iter / preamble) now visible

        // A fragments for both ks of the pair, straight from L2-resident wt
        const char* wb = (const char*)wt + ((size_t)pr << 15);
        s16x8 af[2][2];
        #pragma unroll
        for (int h = 0; h < 2; h++)
            #pragma unroll
            for (int mt = 0; mt < 2; mt++)
                af[h][mt] = *(const s16x8*)(wb + h * 16384 +
                                            (moff + mt * 16 + l16) * 64 + quad * 16);

        // pipeline: sample next pair into the other buffer
        int prn = pr + 1;
        if (prn < NPAIR) {
            if ((prn & 3) == 0) {           // new kernel point: reload taps
                int k2 = prn >> 2;
                i32x4 ti = *(const i32x4*)&tidx[k2][px][0];
                f32x4 tw = *(const f32x4*)&twgt[k2][px][0];
                #pragma unroll
                for (int t = 0; t < 4; t++) { tio[t] = ti[t]; twv[t] = tw[t]; }
            }
            sample_into(prn);
        }

        // B fragments + MFMA on current buffer (both halves of the pair)
        #pragma unroll
        for (int h = 0; h < 2; h++) {
            s16x8 bfr[4];
            #pragma unroll
            for (int nt = 0; nt < 4; nt++)
                bfr[nt] = *(const s16x8*)&Sl[pr & 1][h][nt * 16 + l16][quad * 8];
            #pragma unroll
            for (int mt = 0; mt < 2; mt++)
                #pragma unroll
                for (int nt = 0; nt < 4; nt++)
                    acc[mt][nt] = __builtin_amdgcn_mfma_f32_16x16x32_bf16(
                        af[h][mt], bfr[nt], acc[mt][nt], 0, 0, 0);
        }
    }

    // epilogue: C/D layout row(m)=quad*4+r, col(n)=l16
    float* op = out + ((size_t)b * Oo) * Pp + p0;
    #pragma unroll
    for (int mt = 0; mt < 2; mt++)
        #pragma unroll
        for (int nt = 0; nt < 4; nt++)
            #pragma unroll
            for (int r = 0; r < 4; r++) {
                int o_ = moff + mt * 16 + quad * 4 + r;
                int p_ = nt * 16 + l16;
                op[(size_t)o_ * Pp + p_] = acc[mt][nt][r];
            }
}

extern "C" void kernel_launch(void* const* d_in, const int* in_sizes, int n_in,
                              void* d_out, int out_size, void* d_ws, size_t ws_size,
                              hipStream_t stream) {
    (void)in_sizes; (void)n_in; (void)out_size; (void)ws_size;
    const float* x   = (const float*)d_in[0];
    const float* off = (const float*)d_in[1];
    const float* w   = (const float*)d_in[2];
    float* out = (float*)d_out;

    unsigned short* wt = (unsigned short*)d_ws;
    unsigned short* xt = (unsigned short*)((char*)d_ws + WT_BYTES);

    hipLaunchKernelGGL(prep_weight, dim3(32), dim3(256), 0, stream, w, wt);
    hipLaunchKernelGGL(prep_x, dim3(64, 4, 8), dim3(256), 0, stream, x, xt);
    hipLaunchKernelGGL(dcn_main, dim3(512), dim3(512), 0, stream, off, wt, xt, out);
}

// Round 4
// 147.500 us; speedup vs baseline: 1.5682x; 1.1233x over previous
//
#include <hip/hip_runtime.h>
#include <stdint.h>

// DCN v1 forward: B=8, C=256, H=W=64, K=3, pad=1, stride=1, O=256.
// Round 4: (1) software-pipelined dcn_main: gathers + A-frag prefetch for
// pair k+1 issued before MFMA(pair k) -> global latency hidden under MFMA;
// hand-unrolled x2 for A-register double-buffer. (2) dropped AND-masks in
// bf16 unpack (rel err <2^-8, random). (3) prep fused into ONE kernel:
// float4 reads + uint4 stores (16B/lane both ways), 64-block weight prep.

#define Bb 8
#define Cc 256
#define Hh 64
#define Ww 64
#define Pp 4096
#define Oo 256
#define NK2 9
#define NPAIR 36             // 36 pairs of K-steps (BK=64 each)
#define BN 64
#define SROW 40              // padded S row stride (elems)
#define WT_BYTES (2u * 72u * 256u * 32u)  // 1,179,648

typedef __attribute__((ext_vector_type(4))) float f32x4;
typedef __attribute__((ext_vector_type(8))) short s16x8;
typedef __attribute__((ext_vector_type(4))) int   i32x4;

static __device__ __forceinline__ unsigned short f2bf(float f) {
    union { float f; uint32_t u; } v; v.f = f;
    return (unsigned short)((v.u + 0x7fffu + ((v.u >> 16) & 1u)) >> 16);  // RNE
}
static __device__ __forceinline__ int imin(int a, int b) { return a < b ? a : b; }
static __device__ __forceinline__ int imax(int a, int b) { return a > b ? a : b; }

// ---------------- fused prep: x-transpose (blocks 0..2047) + weight (2048..2111)
// xT[b][p][c] bf16 ; wt[ks(72)][oc(256)][c32(32)] bf16, ks = k2*8+cch.
__global__ __launch_bounds__(256)
void prep(const float* __restrict__ x, const float* __restrict__ w,
          unsigned short* __restrict__ xt, unsigned short* __restrict__ wt) {
    __shared__ __align__(16) unsigned short L[9216];   // 18 KB, dual-purpose
    const int bx = blockIdx.x, tid = threadIdx.x;

    if (bx < 2048) {
        // ---- x: tile 64 c x 64 px ; b = bx&7 keeps XCD affinity with dcn_main
        unsigned short (*t2)[72] = (unsigned short(*)[72])L;  // 64 x 72 shorts
        const int b = bx & 7, ti = bx >> 3;
        const int c0 = (ti & 3) * 64, p0 = (ti >> 2) * 64;
        #pragma unroll
        for (int rd = 0; rd < 4; rd++) {
            int c = (tid >> 4) + rd * 16;
            int px4 = (tid & 15) * 4;
            f32x4 fv = *(const f32x4*)&x[(size_t)(b * Cc + c0 + c) * Pp + p0 + px4];
            #pragma unroll
            for (int j = 0; j < 4; j++) {
                int px = px4 + j;
                int chunk = ((c >> 3) + px) & 7;      // rotate chunks to spread banks
                t2[px][chunk * 8 + (c & 7)] = f2bf(fv[j]);
            }
        }
        __syncthreads();
        #pragma unroll
        for (int rd = 0; rd < 2; rd++) {
            int px = (tid >> 3) + rd * 32;
            int k = tid & 7;
            int chunk = (k + px) & 7;
            uint4 u = *(const uint4*)&t2[px][chunk * 8];
            *(uint4*)&xt[(size_t)(b * Pp + p0 + px) * Cc + c0 + k * 8] = u;
        }
    } else {
        // ---- weight: 64 blocks x 4 o-rows
        const int o0 = (bx - 2048) * 4;
        #pragma unroll
        for (int r9 = 0; r9 < 9; r9++) {
            int idx = r9 * 256 + tid;                  // 0..2303 float4s over 4 rows
            f32x4 fv = *(const f32x4*)&w[(size_t)o0 * 2304 + (size_t)idx * 4];
            #pragma unroll
            for (int j = 0; j < 4; j++) L[idx * 4 + j] = f2bf(fv[j]);
        }
        __syncthreads();
        #pragma unroll 4
        for (int i = 0; i < 36; i++) {
            int ks = i * 2 + (tid >> 7);
            int r = (tid >> 5) & 3, c32 = tid & 31;
            int c = (ks & 7) * 32 + c32, k2 = ks >> 3;
            wt[(size_t)ks * 8192 + (o0 + r) * 32 + c32] = L[r * 2304 + c * 9 + k2];
        }
    }
}

// ---------------- fused sampler + GEMM, software-pipelined.
// Block: 512 thr = 8 waves, each wave 32(M) x 64(N). Grid: 512 flat, b = bx&7.
__global__ __launch_bounds__(512, 4)
void dcn_main(const float* __restrict__ off, const unsigned short* __restrict__ wt,
              const unsigned short* __restrict__ xt, float* __restrict__ out) {
    __shared__ __align__(16) unsigned short Sl[2][2][BN][SROW];  // 20480 B
    __shared__ __align__(16) int   tidx[NK2][BN][4];             // 9216 B (byte offs)
    __shared__ __align__(16) float twgt[NK2][BN][4];             // 9216 B

    const int b   = blockIdx.x & 7;
    const int p0  = (blockIdx.x >> 3) * BN;
    const int tid = threadIdx.x;
    const int lane = tid & 63;
    const int wv   = tid >> 6;
    const int quad = lane >> 4;
    const int l16  = lane & 15;
    const int moff = wv * 32;

    const int px  = tid >> 3;          // sampler: 8 threads/pixel
    const int sub = tid & 7;
    const int hh_ = sub >> 2;
    const int cc_ = (sub & 3) * 8;

    const char* xtb = (const char*)xt + (size_t)b * Pp * Cc * 2;

    // ---- taps for all 9 kernel points ----
    for (int t = tid; t < NK2 * BN; t += 512) {
        int k2 = t >> 6, pxl = t & 63;
        int pl = p0 + pxl;
        int hh = pl >> 6, ww = pl & 63;
        int ky = k2 / 3, kx = k2 - ky * 3;
        float dy = off[((size_t)(b * 18 + 2 * k2    ) * Pp) + pl];
        float dx = off[((size_t)(b * 18 + 2 * k2 + 1) * Pp) + pl];
        float py  = (float)(hh - 1 + ky) + dy;
        float pxf = (float)(ww - 1 + kx) + dx;
        float y0f = floorf(py), x0f = floorf(pxf);
        int   y0 = (int)y0f,  x0 = (int)x0f;
        int   y1 = y0 + 1,    x1 = x0 + 1;
        float ly = py - y0f,  lx = pxf - x0f;
        float oy = 1.f - ly,  ox = 1.f - lx;
        bool vy0 = (y0 >= 0) && (y0 < Hh);
        bool vy1 = (y1 >= 0) && (y1 < Hh);
        bool vx0 = (x0 >= 0) && (x0 < Ww);
        bool vx1 = (x1 >= 0) && (x1 < Ww);
        int cy0 = imin(imax(y0, 0), Hh - 1), cy1 = imin(imax(y1, 0), Hh - 1);
        int cx0 = imin(imax(x0, 0), Ww - 1), cx1 = imin(imax(x1, 0), Ww - 1);
        tidx[k2][pxl][0] = (cy0 * Ww + cx0) * 512;  twgt[k2][pxl][0] = (vy0 && vx0) ? oy * ox : 0.f;
        tidx[k2][pxl][1] = (cy0 * Ww + cx1) * 512;  twgt[k2][pxl][1] = (vy0 && vx1) ? oy * lx : 0.f;
        tidx[k2][pxl][2] = (cy1 * Ww + cx0) * 512;  twgt[k2][pxl][2] = (vy1 && vx0) ? ly * ox : 0.f;
        tidx[k2][pxl][3] = (cy1 * Ww + cx1) * 512;  twgt[k2][pxl][3] = (vy1 && vx1) ? ly * lx : 0.f;
    }
    __syncthreads();

    int   tio[4];
    float twv[4];
    uint4 g[4];
    {
        i32x4 ti = *(const i32x4*)&tidx[0][px][0];
        f32x4 tw = *(const f32x4*)&twgt[0][px][0];
        #pragma unroll
        for (int t = 0; t < 4; t++) { tio[t] = ti[t]; twv[t] = tw[t]; }
    }

    f32x4 acc[2][4];
    #pragma unroll
    for (int mt = 0; mt < 2; mt++)
        #pragma unroll
        for (int nt = 0; nt < 4; nt++) acc[mt][nt] = (f32x4){0.f, 0.f, 0.f, 0.f};

    // reduce gathered taps (in g) -> pack bf16 -> store into Sl[prn&1]
    auto reduce_store = [&](int prn) {
        float s0 = 0.f, s1 = 0.f, s2 = 0.f, s3 = 0.f, s4 = 0.f, s5 = 0.f, s6 = 0.f, s7 = 0.f;
        #pragma unroll
        for (int t = 0; t < 4; t++) {
            uint4 v = g[t];
            float wg = twv[t];
            s0 += wg * __uint_as_float(v.x << 16);
            s1 += wg * __uint_as_float(v.x);          // low bits = mantissa noise <2^-8
            s2 += wg * __uint_as_float(v.y << 16);
            s3 += wg * __uint_as_float(v.y);
            s4 += wg * __uint_as_float(v.z << 16);
            s5 += wg * __uint_as_float(v.z);
            s6 += wg * __uint_as_float(v.w << 16);
            s7 += wg * __uint_as_float(v.w);
        }
        uint4 d;
        d.x = __builtin_amdgcn_perm(__float_as_uint(s1), __float_as_uint(s0), 0x07060302u);
        d.y = __builtin_amdgcn_perm(__float_as_uint(s3), __float_as_uint(s2), 0x07060302u);
        d.z = __builtin_amdgcn_perm(__float_as_uint(s5), __float_as_uint(s4), 0x07060302u);
        d.w = __builtin_amdgcn_perm(__float_as_uint(s7), __float_as_uint(s6), 0x07060302u);
        *(uint4*)&Sl[prn & 1][hh_][px][cc_] = d;
    };

    s16x8 afA[2][2], afB[2][2];

    // one pipelined K-pair step: consume `cur` + Sl[pr&1]; prefetch pair pr+1
    auto step = [&](int pr, s16x8 (&cur)[2][2], s16x8 (&nxt)[2][2]) {
        __syncthreads();                       // Sl[pr&1] now visible
        const int prn = pr + 1;
        if (prn < NPAIR) {
            if ((prn & 3) == 0) {              // new kernel point: reload taps
                int k2 = prn >> 2;
                i32x4 ti = *(const i32x4*)&tidx[k2][px][0];
                f32x4 tw = *(const f32x4*)&twgt[k2][px][0];
                #pragma unroll
                for (int t = 0; t < 4; t++) { tio[t] = ti[t]; twv[t] = tw[t]; }
            }
            const int coff = (prn & 3) * 128 + sub * 16;
            #pragma unroll
            for (int t = 0; t < 4; t++)        // gathers first (oldest in vm queue)
                g[t] = *(const uint4*)(xtb + tio[t] + coff);
            const char* wb = (const char*)wt + ((size_t)prn << 15);
            #pragma unroll
            for (int h = 0; h < 2; h++)        // A-prefetch for pr+1
                #pragma unroll
                for (int mt = 0; mt < 2; mt++)
                    nxt[h][mt] = *(const s16x8*)(wb + h * 16384 +
                                                 (moff + mt * 16 + l16) * 64 + quad * 16);
        }
        // B fragments + MFMA on current buffer (overlaps the loads above)
        s16x8 bfr[2][4];
        const char* sb = (const char*)&Sl[pr & 1][0][0][0];
        #pragma unroll
        for (int h = 0; h < 2; h++)
            #pragma unroll
            for (int nt = 0; nt < 4; nt++)
                bfr[h][nt] = *(const s16x8*)(sb + h * (BN * SROW * 2) +
                                             (nt * 16 + l16) * (SROW * 2) + quad * 16);
        #pragma unroll
        for (int h = 0; h < 2; h++)
            #pragma unroll
            for (int mt = 0; mt < 2; mt++)
                #pragma unroll
                for (int nt = 0; nt < 4; nt++)
                    acc[mt][nt] = __builtin_amdgcn_mfma_f32_16x16x32_bf16(
                        cur[h][mt], bfr[h][nt], acc[mt][nt], 0, 0, 0);
        if (prn < NPAIR) reduce_store(prn);    // waits on gathers only
    };

    // preamble: gathers + A for pair 0; build Sl[0]
    {
        #pragma unroll
        for (int t = 0; t < 4; t++)
            g[t] = *(const uint4*)(xtb + tio[t] + sub * 16);
        const char* wb = (const char*)wt;
        #pragma unroll
        for (int h = 0; h < 2; h++)
            #pragma unroll
            for (int mt = 0; mt < 2; mt++)
                afA[h][mt] = *(const s16x8*)(wb + h * 16384 +
                                             (moff + mt * 16 + l16) * 64 + quad * 16);
        reduce_store(0);
    }

    for (int pr = 0; pr < NPAIR; pr += 2) {
        step(pr,     afA, afB);
        step(pr + 1, afB, afA);
    }

    // epilogue: C/D layout row(m)=quad*4+r, col(n)=l16
    float* op = out + ((size_t)b * Oo) * Pp + p0;
    #pragma unroll
    for (int mt = 0; mt < 2; mt++)
        #pragma unroll
        for (int nt = 0; nt < 4; nt++)
            #pragma unroll
            for (int r = 0; r < 4; r++) {
                int o_ = moff + mt * 16 + quad * 4 + r;
                int p_ = nt * 16 + l16;
                op[(size_t)o_ * Pp + p_] = acc[mt][nt][r];
            }
}

extern "C" void kernel_launch(void* const* d_in, const int* in_sizes, int n_in,
                              void* d_out, int out_size, void* d_ws, size_t ws_size,
                              hipStream_t stream) {
    (void)in_sizes; (void)n_in; (void)out_size; (void)ws_size;
    const float* x   = (const float*)d_in[0];
    const float* off = (const float*)d_in[1];
    const float* w   = (const float*)d_in[2];
    float* out = (float*)d_out;

    unsigned short* wt = (unsigned short*)d_ws;
    unsigned short* xt = (unsigned short*)((char*)d_ws + WT_BYTES);

    hipLaunchKernelGGL(prep, dim3(2112), dim3(256), 0, stream, x, w, xt, wt);
    hipLaunchKernelGGL(dcn_main, dim3(512), dim3(512), 0, stream, off, wt, xt, out);
}